// Round 7
// baseline (227.199 us; speedup 1.0000x reference)
//
#include <hip/hip_runtime.h>
#include <stdint.h>

typedef unsigned short u16;
typedef __bf16 bf16x8 __attribute__((ext_vector_type(8)));
typedef __bf16 bf16x4 __attribute__((ext_vector_type(4)));
typedef float f32x4 __attribute__((ext_vector_type(4)));

#define T_SEQ 2048
#define KVH 4

__device__ __forceinline__ u16 f2b(float f) {
  uint32_t u = __builtin_bit_cast(uint32_t, f);
  u += 0x7FFFu + ((u >> 16) & 1u);
  return (u16)(u >> 16);
}
__device__ __forceinline__ float b2f(u16 h) {
  uint32_t u = ((uint32_t)h) << 16;
  return __builtin_bit_cast(float, u);
}

__device__ __forceinline__ void gload16(const void* g, void* l) {
  __builtin_amdgcn_global_load_lds((const __attribute__((address_space(1))) void*)g,
                                   (__attribute__((address_space(3))) void*)l, 16, 0, 0);
}

// ---------------- fp32 -> bf16 convert (x) ----------------
__global__ void k_f32_to_bf16(const float* __restrict__ in, u16* __restrict__ out, int n4) {
  int i = blockIdx.x * blockDim.x + threadIdx.x;
  if (i >= n4) return;
  float4 v = reinterpret_cast<const float4*>(in)[i];
  ushort4 o;
  o.x = f2b(v.x); o.y = f2b(v.y); o.z = f2b(v.z); o.w = f2b(v.w);
  reinterpret_cast<ushort4*>(out)[i] = o;
}

// ---------------- tiled transpose fp32[R][C] -> bf16[C][R] ----------------
__global__ void k_transpose_f32_bf16(const float* __restrict__ in, u16* __restrict__ out,
                                     int R, int Cc) {
  __shared__ float tile[32][33];
  const int c0 = blockIdx.x * 32, r0 = blockIdx.y * 32;
  const int tx = threadIdx.x, ty = threadIdx.y;
  for (int i = ty; i < 32; i += 8) tile[i][tx] = in[(size_t)(r0 + i) * Cc + c0 + tx];
  __syncthreads();
  for (int i = ty; i < 32; i += 8) out[(size_t)(c0 + i) * R + r0 + tx] = f2b(tile[tx][i]);
}

// ---------------- bf16 GEMM: C[M][N] = A[M][K] * Bt[N][K]^T ----------------
// 128x128 tile, 4 waves (2x2), BK=32, 16x16x32 MFMA, global_load_lds staging.
template <int OUT_BF16>
__global__ __launch_bounds__(256, 3) void k_gemm(const u16* __restrict__ A,
                                                 const u16* __restrict__ Bt,
                                                 void* __restrict__ Cp,
                                                 int M, int N, int Kd,
                                                 int lda, int ldb, int ldc) {
  __align__(16) __shared__ u16 As[128 * 32];
  __align__(16) __shared__ u16 Bs[128 * 32];
  const int tid = threadIdx.x;
  const int wid = tid >> 6, lane = tid & 63;
  const int lg = lane >> 4, lm = lane & 15;
  const int bm = blockIdx.x, bn = blockIdx.y;
  const int wr = wid >> 1, wc = wid & 1;

  const int srow = wid * 32 + (lane >> 2);
  const int scol = (lane & 3) * 8;
  const u16* ap0 = A + (size_t)(bm * 128 + srow) * lda + scol;
  const u16* ap1 = ap0 + (size_t)16 * lda;
  const u16* bp0 = Bt + (size_t)(bn * 128 + srow) * ldb + scol;
  const u16* bp1 = bp0 + (size_t)16 * ldb;
  u16* asDst0 = As + wid * 1024;
  u16* asDst1 = As + wid * 1024 + 512;
  u16* bsDst0 = Bs + wid * 1024;
  u16* bsDst1 = Bs + wid * 1024 + 512;

  const f32x4 z4 = {0.f, 0.f, 0.f, 0.f};
  f32x4 acc[4][4];
#pragma unroll
  for (int i = 0; i < 4; ++i)
#pragma unroll
    for (int j = 0; j < 4; ++j) acc[i][j] = z4;

  const int nk = Kd >> 5;
  for (int kb = 0; kb < nk; ++kb) {
    gload16(ap0, asDst0);
    gload16(ap1, asDst1);
    gload16(bp0, bsDst0);
    gload16(bp1, bsDst1);
    ap0 += 32; ap1 += 32; bp0 += 32; bp1 += 32;
    __syncthreads();
    bf16x8 af[4], bfr[4];
#pragma unroll
    for (int i = 0; i < 4; ++i)
      af[i] = *(const bf16x8*)(As + (wr * 64 + i * 16 + lm) * 32 + lg * 8);
#pragma unroll
    for (int j = 0; j < 4; ++j)
      bfr[j] = *(const bf16x8*)(Bs + (wc * 64 + j * 16 + lm) * 32 + lg * 8);
#pragma unroll
    for (int i = 0; i < 4; ++i)
#pragma unroll
      for (int j = 0; j < 4; ++j)
        acc[i][j] = __builtin_amdgcn_mfma_f32_16x16x32_bf16(af[i], bfr[j], acc[i][j], 0, 0, 0);
    __syncthreads();
  }

#pragma unroll
  for (int i = 0; i < 4; ++i) {
    const int row = bm * 128 + wr * 64 + i * 16 + lg * 4;
#pragma unroll
    for (int j = 0; j < 4; ++j) {
      const int col = bn * 128 + wc * 64 + j * 16 + lm;
#pragma unroll
      for (int r = 0; r < 4; ++r) {
        const float v = acc[i][j][r];
        if (OUT_BF16)
          ((u16*)Cp)[(size_t)(row + r) * ldc + col] = __builtin_bit_cast(u16, (__bf16)v);
        else
          ((float*)Cp)[(size_t)(row + r) * ldc + col] = v;
      }
    }
  }
}

// ---------------- RoPE for K, layout [b][kh][t][h] ----------------
__global__ void k_rope_k(const u16* __restrict__ qkv, u16* __restrict__ kbf) {
  const int idx = blockIdx.x * 256 + threadIdx.x;  // B*T*KVH*64 threads
  const int j = idx & 63;
  const int kh = (idx >> 6) & 3;
  const int m = idx >> 8;  // b*T + t
  const int t = m & (T_SEQ - 1);
  const int b = m >> 11;
  const float inv = __expf((float)j * -0.14391157f);
  const float ang = (float)t * inv;
  float s, c;
  __sincosf(ang, &s, &c);
  const u16* row = qkv + (size_t)m * 3072 + 2048 + kh * 128;
  const float x1 = b2f(row[j]), x2 = b2f(row[j + 64]);
  u16* orow = kbf + ((size_t)(b * KVH + kh) * T_SEQ + t) * 128;
  orow[j] = f2b(x1 * c - x2 * s);
  orow[j + 64] = f2b(x2 * c + x1 * s);
}

// ---------------- V transpose: qkv[.,2560+kh*128+h] -> vt[b][kh][h][t] ----------------
__global__ void k_v_transpose(const u16* __restrict__ qkv, u16* __restrict__ vt) {
  __shared__ u16 tile[32][33];
  const int t0 = blockIdx.x * 32, h0 = blockIdx.y * 32, bk = blockIdx.z;
  const int b = bk >> 2, kh = bk & 3;
  const int tx = threadIdx.x, ty = threadIdx.y;
  for (int i = ty; i < 32; i += 8)
    tile[i][tx] = qkv[(size_t)(b * T_SEQ + t0 + i) * 3072 + 2560 + kh * 128 + h0 + tx];
  __syncthreads();
  for (int i = ty; i < 32; i += 8)
    vt[(size_t)bk * (128 * T_SEQ) + (size_t)(h0 + i) * T_SEQ + t0 + tx] = tile[tx][i];
}

// ---------------- Flash attention with tanh softcap + causal ----------------
// grid (16, N=16, B=2), 8 waves x 32 Q rows. Waves 0-3 (half=0) take the EVEN
// 32-row KV sub-tile of each 64-row step, waves 4-7 the ODD one (fixed-max
// softmax => partials just add; halves combined in LDS at the end).
// 4-deep staging pipeline with COUNTED vmcnt (T3+T4): body(j) =
// { STAGE(j+2); s_waitcnt vmcnt(8); s_barrier; compute(j) } — stage j was
// issued 2 iters ago so the wait is ~free; never vmcnt(0) in the main loop.
// Buffer overwrite safe: STAGE(j+2) targets the buffer last read at
// compute(j-2), separated by the barrier in body(j-1).
// LDS: K 4buf x 2half x 8KB = 64KB | V same = 64KB | P 8x2KB = 16KB -> 144KB.
__global__ __launch_bounds__(512, 1) void k_attn(const u16* __restrict__ qkv,
                                                 const u16* __restrict__ kbf,
                                                 const u16* __restrict__ vt,
                                                 u16* __restrict__ enc) {
  __shared__ __align__(16) u16 smem[73728];  // 147456 B

  const int n = blockIdx.y, b = blockIdx.z;
  const int qt = (b == 0) ? (15 - blockIdx.x) : blockIdx.x;  // balanced pairing
  const int kh = n >> 2;
  const int tid = threadIdx.x;
  const int wid = tid >> 6;
  const int half = wid >> 2;   // 0: even 32-row KV sub-tile, 1: odd
  const int wq = wid & 3;      // Q sub-tile index
  const int lane = tid & 63;
  const int lg = lane >> 4;
  const int lm = lane & 15;
  const int q0w = qt * 128 + wq * 32;         // wave's first Q row
  u16* const Pl = smem + 65536 + wid * 1024;  // per-wave P bounce [16][32] swizzled

  // Q load from qkv + in-register RoPE + 1/sqrt(H) scale (verified R5/R6)
  bf16x8 qfA[4], qfB[4];
  {
    const u16* qa = qkv + (size_t)(b * T_SEQ + q0w + lm) * 3072 + n * 128 + lg * 8;
    const u16* qb_ = qa + 16 * 3072;
    bf16x8 ra[4], rb[4];
#pragma unroll
    for (int c = 0; c < 4; ++c) {
      ra[c] = *(const bf16x8*)(qa + c * 32);
      rb[c] = *(const bf16x8*)(qb_ + c * 32);
    }
    const float scale = 0.08838834764831845f;  // 1/sqrt(128)
    const float tA = (float)(q0w + lm), tB = (float)(q0w + 16 + lm);
#pragma unroll
    for (int c = 0; c < 2; ++c) {
#pragma unroll
      for (int k = 0; k < 8; ++k) {
        const float inv = __expf((float)(c * 32 + lg * 8 + k) * -0.14391157f);
        float sA, cA, sB, cB;
        __sincosf(tA * inv, &sA, &cA);
        __sincosf(tB * inv, &sB, &cB);
        const float a1 = (float)ra[c][k], a2 = (float)ra[c + 2][k];
        const float b1 = (float)rb[c][k], b2 = (float)rb[c + 2][k];
        qfA[c][k]     = (__bf16)((a1 * cA - a2 * sA) * scale);
        qfA[c + 2][k] = (__bf16)((a2 * cA + a1 * sA) * scale);
        qfB[c][k]     = (__bf16)((b1 * cB - b2 * sB) * scale);
        qfB[c + 2][k] = (__bf16)((b2 * cB + b1 * sB) * scale);
      }
    }
  }
  const u16* const kg = kbf + (size_t)(b * KVH + kh) * T_SEQ * 128;
  const u16* const vg = vt + (size_t)(b * KVH + kh) * 128 * T_SEQ;

  // swizzled LDS read offsets. K tile [32][128]: 16B-unit ^= (row&7).
  // V tile [128][32] and P tile [16][32]: 4 units/row, unit ^= (row&3).
  int koff[4];
#pragma unroll
  for (int c = 0; c < 4; ++c) koff[c] = lm * 128 + (((c * 4 + lg) ^ (lm & 7)) * 8);
  const int voffb = lm * 32 + ((lg ^ (lm & 3)) * 8);  // V and P read base
  int poff[2];
#pragma unroll
  for (int st = 0; st < 2; ++st)
    poff[st] = lm * 32 + (((st * 2 + (lg >> 1)) ^ (lm & 3)) * 8) + (lg & 1) * 4;

  const f32x4 z4 = {0.f, 0.f, 0.f, 0.f};
  f32x4 accA[8], accB[8];
#pragma unroll
  for (int h = 0; h < 8; ++h) { accA[h] = z4; accB[h] = z4; }
  float lA = 0.f, lB = 0.f;

  const int ntiles = 2 * qt + 2;  // 64-KV steps (each wave does its 32-row half)

  // stage step j2 (both halves): 4 gload16/thread. Linear LDS dest,
  // inverse-swizzled global source (G21).
  auto STAGE = [&](int buf, int j2) {
#pragma unroll
    for (int hh = 0; hh < 2; ++hh) {
      const int kv2 = j2 * 64 + hh * 32;
      {
        const int row = tid >> 4, u = tid & 15;  // K: 32 rows x 16 units
        gload16(kg + (size_t)(kv2 + row) * 128 + ((u ^ (row & 7)) * 8),
                smem + (buf * 2 + hh) * 4096 + tid * 8);
      }
      {
        const int row = tid >> 2, u = tid & 3;   // V: 128 rows x 4 units
        gload16(vg + (size_t)row * T_SEQ + kv2 + ((u ^ (row & 3)) * 8),
                smem + 32768 + (buf * 2 + hh) * 4096 + tid * 8);
      }
    }
  };

  // fixed-max softcap+softmax for one 16-row sub-tile (8 p-elements)
  auto tile_pc = [&](f32x4* sa, float* p, float& lsum, int tg, bool needMask, int kvh) {
#pragma unroll
    for (int st = 0; st < 2; ++st)
#pragma unroll
      for (int r = 0; r < 4; ++r) p[st * 4 + r] = sa[st][r];
#pragma unroll
    for (int i = 0; i < 8; ++i) {
      const float e = __builtin_amdgcn_exp2f(p[i] * 0.05770780163555853f);
      p[i] = __builtin_amdgcn_exp2f(-144.269504088896f * __builtin_amdgcn_rcpf(e + 1.f));
    }
    if (needMask) {
#pragma unroll
      for (int i = 0; i < 8; ++i) {
        const int sg = kvh + (i >> 2) * 16 + lg * 4 + (i & 3);
        if (sg > tg) p[i] = 0.f;
      }
    }
#pragma unroll
    for (int i = 0; i < 8; ++i) lsum += p[i];
  };
  auto tile_pw = [&](const float* p) {
#pragma unroll
    for (int st = 0; st < 2; ++st) {
      bf16x4 w4;
#pragma unroll
      for (int r = 0; r < 4; ++r) w4[r] = (__bf16)p[st * 4 + r];
      *(bf16x4*)(Pl + poff[st]) = w4;
    }
  };

  auto COMPUTE = [&](int j) {
    const int kvh = j * 64 + half * 32;
    if (kvh > q0w + 31) return;  // fully masked for this wave
    const u16* KsC = smem + ((j & 3) * 2 + half) * 4096;
    const u16* VsC = smem + 32768 + ((j & 3) * 2 + half) * 4096;

    f32x4 saA[2] = {z4, z4}, saB[2] = {z4, z4};
    __builtin_amdgcn_s_setprio(1);
#pragma unroll
    for (int st = 0; st < 2; ++st) {
#pragma unroll
      for (int c = 0; c < 4; ++c) {
        const bf16x8 kf = *(const bf16x8*)(KsC + st * 2048 + koff[c]);
        saA[st] = __builtin_amdgcn_mfma_f32_16x16x32_bf16(kf, qfA[c], saA[st], 0, 0, 0);
        saB[st] = __builtin_amdgcn_mfma_f32_16x16x32_bf16(kf, qfB[c], saB[st], 0, 0, 0);
      }
    }
    __builtin_amdgcn_s_setprio(0);

    float pA[8], pB[8];
    tile_pc(saA, pA, lA, q0w + lm, kvh + 31 > q0w, kvh);
    tile_pw(pA);
    tile_pc(saB, pB, lB, q0w + 16 + lm, kvh + 31 > q0w + 16, kvh);
    asm volatile("s_waitcnt lgkmcnt(0)" ::: "memory");
    const bf16x8 pfA = *(const bf16x8*)(Pl + voffb);
    tile_pw(pB);
    asm volatile("s_waitcnt lgkmcnt(0)" ::: "memory");
    const bf16x8 pfB = *(const bf16x8*)(Pl + voffb);

    __builtin_amdgcn_s_setprio(1);
#pragma unroll
    for (int h = 0; h < 8; ++h) {
      const bf16x8 vf = *(const bf16x8*)(VsC + h * 512 + voffb);
      accA[h] = __builtin_amdgcn_mfma_f32_16x16x32_bf16(pfA, vf, accA[h], 0, 0, 0);
      accB[h] = __builtin_amdgcn_mfma_f32_16x16x32_bf16(pfB, vf, accB[h], 0, 0, 0);
    }
    __builtin_amdgcn_s_setprio(0);
  };

  STAGE(0, 0);
  STAGE(1, 1);
  for (int j = 0; j < ntiles - 2; ++j) {
    STAGE((j + 2) & 3, j + 2);
    asm volatile("s_waitcnt vmcnt(8)" ::: "memory");  // stage j landed (j+1,j+2 in flight)
    __builtin_amdgcn_s_barrier();
    __builtin_amdgcn_sched_barrier(0);
    COMPUTE(j);
  }
  {
    asm volatile("s_waitcnt vmcnt(4)" ::: "memory");  // stage ntiles-2 landed
    __builtin_amdgcn_s_barrier();
    __builtin_amdgcn_sched_barrier(0);
    COMPUTE(ntiles - 2);
  }
  {
    asm volatile("s_waitcnt vmcnt(0)" ::: "memory");  // last stage landed
    __builtin_amdgcn_s_barrier();
    __builtin_amdgcn_sched_barrier(0);
    COMPUTE(ntiles - 1);
  }

  // ---- combine halves in LDS (staging buffers dead) ----
  __syncthreads();
  float* const scrO = (float*)smem;           // 16384 floats (K region, 64KB)
  float* const scrL = (float*)smem + 16384;   // (V region)
  if (half == 1) {
    float* w = scrO + wq * 4096 + lane;
#pragma unroll
    for (int h = 0; h < 8; ++h)
#pragma unroll
      for (int r = 0; r < 4; ++r) {
        w[(h * 4 + r) * 64] = accA[h][r];
        w[(32 + h * 4 + r) * 64] = accB[h][r];
      }
    scrL[wq * 128 + lane * 2] = lA;
    scrL[wq * 128 + lane * 2 + 1] = lB;
  }
  __syncthreads();
  if (half == 0) {
    const float* w = scrO + wq * 4096 + lane;
#pragma unroll
    for (int h = 0; h < 8; ++h)
#pragma unroll
      for (int r = 0; r < 4; ++r) {
        accA[h][r] += w[(h * 4 + r) * 64];
        accB[h][r] += w[(32 + h * 4 + r) * 64];
      }
    lA += scrL[wq * 128 + lane * 2];
    lB += scrL[wq * 128 + lane * 2 + 1];

    lA += __shfl_xor(lA, 16); lA += __shfl_xor(lA, 32);
    lB += __shfl_xor(lB, 16); lB += __shfl_xor(lB, 32);
    float liA[4], liB[4];
#pragma unroll
    for (int r = 0; r < 4; ++r) {
      liA[r] = 1.f / __shfl(lA, lg * 4 + r);
      liB[r] = 1.f / __shfl(lB, lg * 4 + r);
    }
#pragma unroll
    for (int h = 0; h < 8; ++h) {
#pragma unroll
      for (int r = 0; r < 4; ++r) {
        const size_t colo = n * 128 + h * 16 + lm;
        enc[(size_t)(b * T_SEQ + q0w + lg * 4 + r) * 2048 + colo] =
            __builtin_bit_cast(u16, (__bf16)(accA[h][r] * liA[r]));
        enc[(size_t)(b * T_SEQ + q0w + 16 + lg * 4 + r) * 2048 + colo] =
            __builtin_bit_cast(u16, (__bf16)(accB[h][r] * liB[r]));
      }
    }
  }
}

extern "C" void kernel_launch(void* const* d_in, const int* in_sizes, int n_in,
                              void* d_out, int out_size, void* d_ws, size_t ws_size,
                              hipStream_t stream) {
  const float* x  = (const float*)d_in[0];
  const float* wq = (const float*)d_in[1];
  const float* wk = (const float*)d_in[2];
  const float* wv = (const float*)d_in[3];
  const float* wo = (const float*)d_in[4];

  char* ws = (char*)d_ws;
  u16* x_bf  = (u16*)(ws);                    // 16,777,216 B
  u16* wqkvt = (u16*)(ws + 16777216);         // 12,582,912 B  [3072][2048]
  u16* wot   = (u16*)(ws + 29360128);         //  8,388,608 B  [2048][2048]
  u16* qkv   = (u16*)(ws + 37748736);         // 25,165,824 B  [4096][3072] (live thru attn)
  u16* enc   = (u16*)(ws + 62914560);         // 16,777,216 B  [4096][2048]
  u16* k_bf  = (u16*)(ws + 79691776);         //  4,194,304 B  [b][kh][t][h]
  u16* vt    = (u16*)(ws + 83886080);         //  4,194,304 B  [b][kh][h][t]
  if (ws_size < 88080384) return;             // need 84 MiB scratch
  (void)in_sizes; (void)n_in; (void)out_size;

  // 1) x -> bf16
  k_f32_to_bf16<<<dim3(8192), dim3(256), 0, stream>>>(x, x_bf, 8388608 / 4);
  // 2) weight transposes (fp32 [K][N] -> bf16 [N][K])
  k_transpose_f32_bf16<<<dim3(64, 64), dim3(32, 8), 0, stream>>>(wq, wqkvt, 2048, 2048);
  k_transpose_f32_bf16<<<dim3(16, 64), dim3(32, 8), 0, stream>>>(wk, wqkvt + 2048 * 2048, 2048, 512);
  k_transpose_f32_bf16<<<dim3(16, 64), dim3(32, 8), 0, stream>>>(wv, wqkvt + 2560 * 2048, 2048, 512);
  k_transpose_f32_bf16<<<dim3(64, 64), dim3(32, 8), 0, stream>>>(wo, wot, 2048, 2048);
  // 3) fused QKV projection: [4096][3072]
  k_gemm<1><<<dim3(32, 24), dim3(256), 0, stream>>>(x_bf, wqkvt, qkv,
                                                    4096, 3072, 2048, 2048, 2048, 3072);
  // 4) K RoPE + V transpose (Q RoPE fused into k_attn)
  k_rope_k<<<dim3(4096), dim3(256), 0, stream>>>(qkv, k_bf);
  k_v_transpose<<<dim3(64, 4, 8), dim3(32, 8), 0, stream>>>(qkv, vt);
  // 5) flash attention -> enc [4096][2048] bf16
  k_attn<<<dim3(16, 16, 2), dim3(512), 0, stream>>>(qkv, k_bf, vt, enc);
  // 6) output projection -> d_out fp32
  k_gemm<0><<<dim3(32, 16), dim3(256), 0, stream>>>(enc, wot, d_out,
                                                    4096, 2048, 2048, 2048, 2048, 2048);
}

// Round 8
// 204.159 us; speedup vs baseline: 1.1129x; 1.1129x over previous
//
#include <hip/hip_runtime.h>
#include <stdint.h>

typedef unsigned short u16;
typedef __bf16 bf16x8 __attribute__((ext_vector_type(8)));
typedef __bf16 bf16x4 __attribute__((ext_vector_type(4)));
typedef float f32x4 __attribute__((ext_vector_type(4)));

#define T_SEQ 2048
#define KVH 4

__device__ __forceinline__ u16 f2b(float f) {
  uint32_t u = __builtin_bit_cast(uint32_t, f);
  u += 0x7FFFu + ((u >> 16) & 1u);
  return (u16)(u >> 16);
}
__device__ __forceinline__ float b2f(u16 h) {
  uint32_t u = ((uint32_t)h) << 16;
  return __builtin_bit_cast(float, u);
}

__device__ __forceinline__ void gload16(const void* g, void* l) {
  __builtin_amdgcn_global_load_lds((const __attribute__((address_space(1))) void*)g,
                                   (__attribute__((address_space(3))) void*)l, 16, 0, 0);
}

// ---------------- fp32 -> bf16 convert (x) ----------------
__global__ void k_f32_to_bf16(const float* __restrict__ in, u16* __restrict__ out, int n4) {
  int i = blockIdx.x * blockDim.x + threadIdx.x;
  if (i >= n4) return;
  float4 v = reinterpret_cast<const float4*>(in)[i];
  ushort4 o;
  o.x = f2b(v.x); o.y = f2b(v.y); o.z = f2b(v.z); o.w = f2b(v.w);
  reinterpret_cast<ushort4*>(out)[i] = o;
}

// ---------------- all 4 weight transposes fused: fp32[R][C] -> bf16[C][R] ----------------
// z=0: wq -> wqkvt[0..2048), z=1: wo -> wot, z=2: bx<16 wk, bx in [16,32) wv.
__global__ void k_transpose_all(const float* __restrict__ wq, const float* __restrict__ wk,
                                const float* __restrict__ wv, const float* __restrict__ wo,
                                u16* __restrict__ wqkvt, u16* __restrict__ wot) {
  __shared__ float tile[32][33];
  const int z = blockIdx.z;
  int bx = blockIdx.x;
  const float* in;
  u16* out;
  int Cc;
  if (z == 0)      { in = wq; out = wqkvt;              Cc = 2048; }
  else if (z == 1) { in = wo; out = wot;                Cc = 2048; }
  else {
    if (bx < 16)      { in = wk; out = wqkvt + 2048 * 2048; Cc = 512; }
    else if (bx < 32) { in = wv; out = wqkvt + 2560 * 2048; Cc = 512; bx -= 16; }
    else return;
  }
  const int R = 2048;
  const int c0 = bx * 32, r0 = blockIdx.y * 32;
  const int tx = threadIdx.x, ty = threadIdx.y;
  for (int i = ty; i < 32; i += 8) tile[i][tx] = in[(size_t)(r0 + i) * Cc + c0 + tx];
  __syncthreads();
  for (int i = ty; i < 32; i += 8) out[(size_t)(c0 + i) * R + r0 + tx] = f2b(tile[tx][i]);
}

// ---------------- bf16 GEMM: C[M][N] = A[M][K] * Bt[N][K]^T ----------------
// 128x128 tile, 4 waves (2x2), BK=32, 16x16x32 MFMA, global_load_lds staging.
// XCD-aware block swizzle (T1): nwg%8==0 for both call sites.
template <int OUT_BF16>
__global__ __launch_bounds__(256, 3) void k_gemm(const u16* __restrict__ A,
                                                 const u16* __restrict__ Bt,
                                                 void* __restrict__ Cp,
                                                 int M, int N, int Kd,
                                                 int lda, int ldb, int ldc) {
  __align__(16) __shared__ u16 As[128 * 32];
  __align__(16) __shared__ u16 Bs[128 * 32];
  const int tid = threadIdx.x;
  const int wid = tid >> 6, lane = tid & 63;
  const int lg = lane >> 4, lm = lane & 15;
  // XCD swizzle: consecutive swizzled ids within an XCD share the B panel.
  const int nwg = gridDim.x * gridDim.y;
  int f = blockIdx.y * gridDim.x + blockIdx.x;
  f = (f & 7) * (nwg >> 3) + (f >> 3);
  const int bm = f % gridDim.x, bn = f / gridDim.x;
  const int wr = wid >> 1, wc = wid & 1;

  const int srow = wid * 32 + (lane >> 2);
  const int scol = (lane & 3) * 8;
  const u16* ap0 = A + (size_t)(bm * 128 + srow) * lda + scol;
  const u16* ap1 = ap0 + (size_t)16 * lda;
  const u16* bp0 = Bt + (size_t)(bn * 128 + srow) * ldb + scol;
  const u16* bp1 = bp0 + (size_t)16 * ldb;
  u16* asDst0 = As + wid * 1024;
  u16* asDst1 = As + wid * 1024 + 512;
  u16* bsDst0 = Bs + wid * 1024;
  u16* bsDst1 = Bs + wid * 1024 + 512;

  const f32x4 z4 = {0.f, 0.f, 0.f, 0.f};
  f32x4 acc[4][4];
#pragma unroll
  for (int i = 0; i < 4; ++i)
#pragma unroll
    for (int j = 0; j < 4; ++j) acc[i][j] = z4;

  const int nk = Kd >> 5;
  for (int kb = 0; kb < nk; ++kb) {
    gload16(ap0, asDst0);
    gload16(ap1, asDst1);
    gload16(bp0, bsDst0);
    gload16(bp1, bsDst1);
    ap0 += 32; ap1 += 32; bp0 += 32; bp1 += 32;
    __syncthreads();
    bf16x8 af[4], bfr[4];
#pragma unroll
    for (int i = 0; i < 4; ++i)
      af[i] = *(const bf16x8*)(As + (wr * 64 + i * 16 + lm) * 32 + lg * 8);
#pragma unroll
    for (int j = 0; j < 4; ++j)
      bfr[j] = *(const bf16x8*)(Bs + (wc * 64 + j * 16 + lm) * 32 + lg * 8);
#pragma unroll
    for (int i = 0; i < 4; ++i)
#pragma unroll
      for (int j = 0; j < 4; ++j)
        acc[i][j] = __builtin_amdgcn_mfma_f32_16x16x32_bf16(af[i], bfr[j], acc[i][j], 0, 0, 0);
    __syncthreads();
  }

#pragma unroll
  for (int i = 0; i < 4; ++i) {
    const int row = bm * 128 + wr * 64 + i * 16 + lg * 4;
#pragma unroll
    for (int j = 0; j < 4; ++j) {
      const int col = bn * 128 + wc * 64 + j * 16 + lm;
#pragma unroll
      for (int r = 0; r < 4; ++r) {
        const float v = acc[i][j][r];
        if (OUT_BF16)
          ((u16*)Cp)[(size_t)(row + r) * ldc + col] = __builtin_bit_cast(u16, (__bf16)v);
        else
          ((float*)Cp)[(size_t)(row + r) * ldc + col] = v;
      }
    }
  }
}

// ---------------- fused: RoPE for K (bid<4096) + V transpose (bid>=4096) ----------------
__global__ void k_rope_v(const u16* __restrict__ qkv, u16* __restrict__ kbf,
                         u16* __restrict__ vt) {
  __shared__ u16 tile[32][33];
  const int bid = blockIdx.x;
  const int tid = threadIdx.x;
  if (bid < 4096) {
    const int idx = bid * 256 + tid;  // B*T*KVH*64 threads
    const int j = idx & 63;
    const int kh = (idx >> 6) & 3;
    const int m = idx >> 8;  // b*T + t
    const int t = m & (T_SEQ - 1);
    const int b = m >> 11;
    const float inv = __expf((float)j * -0.14391157f);
    const float ang = (float)t * inv;
    float s, c;
    __sincosf(ang, &s, &c);
    const u16* row = qkv + (size_t)m * 3072 + 2048 + kh * 128;
    const float x1 = b2f(row[j]), x2 = b2f(row[j + 64]);
    u16* orow = kbf + ((size_t)(b * KVH + kh) * T_SEQ + t) * 128;
    orow[j] = f2b(x1 * c - x2 * s);
    orow[j + 64] = f2b(x2 * c + x1 * s);
  } else {
    const int vb = bid - 4096;  // 2048 blocks: (bx 64, by 4, bz 8)
    const int t0 = (vb & 63) * 32, h0 = ((vb >> 6) & 3) * 32, bk = vb >> 8;
    const int b = bk >> 2, kh = bk & 3;
    const int tx = tid & 31, ty = tid >> 5;
    for (int i = ty; i < 32; i += 8)
      tile[i][tx] = qkv[(size_t)(b * T_SEQ + t0 + i) * 3072 + 2560 + kh * 128 + h0 + tx];
    __syncthreads();
    for (int i = ty; i < 32; i += 8)
      vt[(size_t)bk * (128 * T_SEQ) + (size_t)(h0 + i) * T_SEQ + t0 + tx] = tile[tx][i];
  }
}

// ---------------- Flash attention with tanh softcap + causal (R6 verified) ----------------
// grid (16, N=16, B=2), 4 waves x 32 Q rows (two 16-row sub-tiles A,B).
// 2 blocks/CU. RoPE-Q fused into Q load. FIXED-MAX softmax. Pipelined P bounce.
__global__ __launch_bounds__(256, 2) void k_attn(const u16* __restrict__ qkv,
                                                 const u16* __restrict__ kbf,
                                                 const u16* __restrict__ vt,
                                                 u16* __restrict__ enc) {
  // LDS: Ks dbuf 2*16KB | Vs dbuf 2*16KB | Pl 4 waves * 2KB  = 73728 B
  __shared__ __align__(16) u16 smem[36864];
  u16* const Ks0 = smem;            // + buf*8192
  u16* const Vs0 = smem + 16384;    // + buf*8192

  const int n = blockIdx.y, b = blockIdx.z;
  const int qt = (b == 0) ? (15 - blockIdx.x) : blockIdx.x;  // balanced pairing
  const int kh = n >> 2;
  const int tid = threadIdx.x;
  const int wid = tid >> 6;
  const int lane = tid & 63;
  const int lg = lane >> 4;
  const int lm = lane & 15;
  const int q0w = qt * 128 + wid * 32;        // wave's first Q row
  u16* const Pl = smem + 32768 + wid * 1024;  // [16][64] bf16 swizzled, reused A->B

  // Q load from qkv + in-register RoPE + 1/sqrt(H) scale
  bf16x8 qfA[4], qfB[4];
  {
    const u16* qa = qkv + (size_t)(b * T_SEQ + q0w + lm) * 3072 + n * 128 + lg * 8;
    const u16* qb_ = qa + 16 * 3072;
    bf16x8 ra[4], rb[4];
#pragma unroll
    for (int c = 0; c < 4; ++c) {
      ra[c] = *(const bf16x8*)(qa + c * 32);
      rb[c] = *(const bf16x8*)(qb_ + c * 32);
    }
    const float scale = 0.08838834764831845f;  // 1/sqrt(128)
    const float tA = (float)(q0w + lm), tB = (float)(q0w + 16 + lm);
#pragma unroll
    for (int c = 0; c < 2; ++c) {
#pragma unroll
      for (int k = 0; k < 8; ++k) {
        const float inv = __expf((float)(c * 32 + lg * 8 + k) * -0.14391157f);
        float sA, cA, sB, cB;
        __sincosf(tA * inv, &sA, &cA);
        __sincosf(tB * inv, &sB, &cB);
        const float a1 = (float)ra[c][k], a2 = (float)ra[c + 2][k];
        const float b1 = (float)rb[c][k], b2 = (float)rb[c + 2][k];
        qfA[c][k]     = (__bf16)((a1 * cA - a2 * sA) * scale);
        qfA[c + 2][k] = (__bf16)((a2 * cA + a1 * sA) * scale);
        qfB[c][k]     = (__bf16)((b1 * cB - b2 * sB) * scale);
        qfB[c + 2][k] = (__bf16)((b2 * cB + b1 * sB) * scale);
      }
    }
  }
  const u16* const kg = kbf + (size_t)(b * KVH + kh) * T_SEQ * 128;
  const u16* const vg = vt + (size_t)(b * KVH + kh) * 128 * T_SEQ;

  // swizzled LDS read offsets (elements); 16B-unit ^= (row&7)
  const int swz = lm & 7;
  int koff[4], voff[2], poff[4];
#pragma unroll
  for (int c = 0; c < 4; ++c) koff[c] = lm * 128 + (((c * 4 + lg) ^ swz) * 8);
#pragma unroll
  for (int ks = 0; ks < 2; ++ks) voff[ks] = lm * 64 + (((ks * 4 + lg) ^ swz) * 8);
#pragma unroll
  for (int st = 0; st < 4; ++st)
    poff[st] = lm * 64 + (((st * 2 + (lg >> 1)) ^ swz) * 8) + (lg & 1) * 4;

  const f32x4 z4 = {0.f, 0.f, 0.f, 0.f};
  f32x4 accA[8], accB[8];
#pragma unroll
  for (int h = 0; h < 8; ++h) { accA[h] = z4; accB[h] = z4; }
  float lA = 0.f, lB = 0.f;  // per-lane partial row-sums

  const int ntiles = 2 * qt + 2;

  // stage tile kb2 into buffer buf (linear LDS dest, inverse-swizzled gsrc)
  auto STAGE = [&](int buf, int kb2) {
    const int kv2 = kb2 * 64;
    const u16* ksrc = kg + (size_t)kv2 * 128;
    u16* kdst = Ks0 + buf * 8192;
    u16* vdst = Vs0 + buf * 8192;
#pragma unroll
    for (int i = 0; i < 4; ++i) {
      const int g = tid + i * 256;
      const int row = g >> 4, u = g & 15;
      gload16(ksrc + row * 128 + ((u ^ (row & 7)) * 8), kdst + g * 8);
    }
#pragma unroll
    for (int i = 0; i < 4; ++i) {
      const int g = tid + i * 256;
      const int row = g >> 3, u = g & 7;
      gload16(vg + (size_t)row * T_SEQ + kv2 + ((u ^ (row & 7)) * 8), vdst + g * 8);
    }
  };

  // fixed-max softcap+softmax -> p[16]; no cross-lane ops.
  auto tile_pc = [&](f32x4* sa, float* p, float& lsum, int tg, bool needMask, int kv) {
#pragma unroll
    for (int st = 0; st < 4; ++st)
#pragma unroll
      for (int r = 0; r < 4; ++r) p[st * 4 + r] = sa[st][r];
    // p~ = exp(50*tanh(x/50) - 50) = exp2(-144.269504 / (exp2(x*0.05770780) + 1))
#pragma unroll
    for (int i = 0; i < 16; ++i) {
      const float e = __builtin_amdgcn_exp2f(p[i] * 0.05770780163555853f);
      p[i] = __builtin_amdgcn_exp2f(-144.269504088896f * __builtin_amdgcn_rcpf(e + 1.f));
    }
    if (needMask) {
#pragma unroll
      for (int i = 0; i < 16; ++i) {
        const int sg = kv + (i >> 2) * 16 + lg * 4 + (i & 3);
        if (sg > tg) p[i] = 0.f;
      }
    }
#pragma unroll
    for (int i = 0; i < 16; ++i) lsum += p[i];
  };
  // pack p[16] -> Pl via native bf16 casts (v_cvt_pk_bf16_f32)
  auto tile_pw = [&](const float* p) {
#pragma unroll
    for (int st = 0; st < 4; ++st) {
      bf16x4 w4;
#pragma unroll
      for (int r = 0; r < 4; ++r) w4[r] = (__bf16)p[st * 4 + r];
      *(bf16x4*)(Pl + poff[st]) = w4;
    }
  };

  STAGE(0, 0);
  asm volatile("s_waitcnt vmcnt(0)" ::: "memory");
  __syncthreads();

  for (int kb = 0; kb < ntiles; ++kb) {
    const int cur = kb & 1;
    if (kb + 1 < ntiles) STAGE(cur ^ 1, kb + 1);
    const int kv = kb * 64;
    if (kv <= q0w + 31) {  // wave has unmasked rows in this KV tile
      const u16* KsC = Ks0 + cur * 8192;
      const u16* VsC = Vs0 + cur * 8192;

      f32x4 saA[4] = {z4, z4, z4, z4};
      f32x4 saB[4] = {z4, z4, z4, z4};
      __builtin_amdgcn_s_setprio(1);
#pragma unroll
      for (int st = 0; st < 4; ++st) {
#pragma unroll
        for (int c = 0; c < 4; ++c) {
          const bf16x8 kf = *(const bf16x8*)(KsC + st * 2048 + koff[c]);
          saA[st] = __builtin_amdgcn_mfma_f32_16x16x32_bf16(kf, qfA[c], saA[st], 0, 0, 0);
          saB[st] = __builtin_amdgcn_mfma_f32_16x16x32_bf16(kf, qfB[c], saB[st], 0, 0, 0);
        }
      }
      __builtin_amdgcn_s_setprio(0);

      // pipelined P bounce: A's write latency hidden under B's softcap VALU
      float pA[16], pB[16];
      tile_pc(saA, pA, lA, q0w + lm, kv + 63 > q0w, kv);
      tile_pw(pA);
      tile_pc(saB, pB, lB, q0w + 16 + lm, kv + 63 > q0w + 16, kv);
      asm volatile("s_waitcnt lgkmcnt(0)" ::: "memory");
      bf16x8 pfA[2], pfB[2];
#pragma unroll
      for (int ks = 0; ks < 2; ++ks) pfA[ks] = *(const bf16x8*)(Pl + voff[ks]);
      tile_pw(pB);
      asm volatile("s_waitcnt lgkmcnt(0)" ::: "memory");
#pragma unroll
      for (int ks = 0; ks < 2; ++ks) pfB[ks] = *(const bf16x8*)(Pl + voff[ks]);

      __builtin_amdgcn_s_setprio(1);
#pragma unroll
      for (int h = 0; h < 8; ++h) {
#pragma unroll
        for (int ks = 0; ks < 2; ++ks) {
          const bf16x8 vf = *(const bf16x8*)(VsC + h * 1024 + voff[ks]);
          accA[h] = __builtin_amdgcn_mfma_f32_16x16x32_bf16(pfA[ks], vf, accA[h], 0, 0, 0);
          accB[h] = __builtin_amdgcn_mfma_f32_16x16x32_bf16(pfB[ks], vf, accB[h], 0, 0, 0);
        }
      }
      __builtin_amdgcn_s_setprio(0);
    }
    asm volatile("s_waitcnt vmcnt(0)" ::: "memory");  // next-tile staging landed
    __syncthreads();
  }

  // reduce row-sums across the 4 lg lanes sharing a row, then normalize.
  lA += __shfl_xor(lA, 16); lA += __shfl_xor(lA, 32);
  lB += __shfl_xor(lB, 16); lB += __shfl_xor(lB, 32);
  float liA[4], liB[4];
#pragma unroll
  for (int r = 0; r < 4; ++r) {
    liA[r] = 1.f / __shfl(lA, lg * 4 + r);
    liB[r] = 1.f / __shfl(lB, lg * 4 + r);
  }
#pragma unroll
  for (int h = 0; h < 8; ++h) {
#pragma unroll
    for (int r = 0; r < 4; ++r) {
      const size_t colo = n * 128 + h * 16 + lm;
      enc[(size_t)(b * T_SEQ + q0w + lg * 4 + r) * 2048 + colo] =
          __builtin_bit_cast(u16, (__bf16)(accA[h][r] * liA[r]));
      enc[(size_t)(b * T_SEQ + q0w + 16 + lg * 4 + r) * 2048 + colo] =
          __builtin_bit_cast(u16, (__bf16)(accB[h][r] * liB[r]));
    }
  }
}

extern "C" void kernel_launch(void* const* d_in, const int* in_sizes, int n_in,
                              void* d_out, int out_size, void* d_ws, size_t ws_size,
                              hipStream_t stream) {
  const float* x  = (const float*)d_in[0];
  const float* wq = (const float*)d_in[1];
  const float* wk = (const float*)d_in[2];
  const float* wv = (const float*)d_in[3];
  const float* wo = (const float*)d_in[4];

  char* ws = (char*)d_ws;
  u16* x_bf  = (u16*)(ws);                    // 16,777,216 B
  u16* wqkvt = (u16*)(ws + 16777216);         // 12,582,912 B  [3072][2048]
  u16* wot   = (u16*)(ws + 29360128);         //  8,388,608 B  [2048][2048]
  u16* qkv   = (u16*)(ws + 37748736);         // 25,165,824 B  [4096][3072] (live thru attn)
  u16* enc   = (u16*)(ws + 62914560);         // 16,777,216 B  [4096][2048]
  u16* k_bf  = (u16*)(ws + 79691776);         //  4,194,304 B  [b][kh][t][h]
  u16* vt    = (u16*)(ws + 83886080);         //  4,194,304 B  [b][kh][h][t]
  if (ws_size < 88080384) return;             // need 84 MiB scratch
  (void)in_sizes; (void)n_in; (void)out_size;

  // 1) x -> bf16
  k_f32_to_bf16<<<dim3(8192), dim3(256), 0, stream>>>(x, x_bf, 8388608 / 4);
  // 2) all weight transposes fused (fp32 [K][N] -> bf16 [N][K])
  k_transpose_all<<<dim3(64, 64, 3), dim3(32, 8), 0, stream>>>(wq, wk, wv, wo, wqkvt, wot);
  // 3) fused QKV projection: [4096][3072]
  k_gemm<1><<<dim3(32, 24), dim3(256), 0, stream>>>(x_bf, wqkvt, qkv,
                                                    4096, 3072, 2048, 2048, 2048, 3072);
  // 4) K RoPE + V transpose fused (Q RoPE fused into k_attn)
  k_rope_v<<<dim3(6144), dim3(256), 0, stream>>>(qkv, k_bf, vt);
  // 5) flash attention -> enc [4096][2048] bf16
  k_attn<<<dim3(16, 16, 2), dim3(256), 0, stream>>>(qkv, k_bf, vt, enc);
  // 6) output projection -> d_out fp32
  k_gemm<0><<<dim3(32, 16), dim3(256), 0, stream>>>(enc, wot, d_out,
                                                    4096, 2048, 2048, 2048, 2048, 2048);
}

// Round 9
// 187.412 us; speedup vs baseline: 1.2123x; 1.0894x over previous
//
#include <hip/hip_runtime.h>
#include <stdint.h>

typedef unsigned short u16;
typedef __bf16 bf16x8 __attribute__((ext_vector_type(8)));
typedef __bf16 bf16x4 __attribute__((ext_vector_type(4)));
typedef float f32x4 __attribute__((ext_vector_type(4)));

#define T_SEQ 2048
#define KVH 4

__device__ __forceinline__ u16 f2b(float f) {
  uint32_t u = __builtin_bit_cast(uint32_t, f);
  u += 0x7FFFu + ((u >> 16) & 1u);
  return (u16)(u >> 16);
}
__device__ __forceinline__ float b2f(u16 h) {
  uint32_t u = ((uint32_t)h) << 16;
  return __builtin_bit_cast(float, u);
}

__device__ __forceinline__ void gload16(const void* g, void* l) {
  __builtin_amdgcn_global_load_lds((const __attribute__((address_space(1))) void*)g,
                                   (__attribute__((address_space(3))) void*)l, 16, 0, 0);
}

// ---------------- fused prep: weight transposes (z<3) + x fp32->bf16 (z=3) ----------------
__global__ void k_prep(const float* __restrict__ x, u16* __restrict__ x_bf,
                       const float* __restrict__ wq, const float* __restrict__ wk,
                       const float* __restrict__ wv, const float* __restrict__ wo,
                       u16* __restrict__ wqkvt, u16* __restrict__ wot) {
  const int z = blockIdx.z;
  const int tid = threadIdx.y * 32 + threadIdx.x;
  if (z == 3) {  // x -> bf16: 4096 blocks x 256 thr x 2 float4
    const int base = (blockIdx.y * 64 + blockIdx.x) * 256 + tid;
#pragma unroll
    for (int rep = 0; rep < 2; ++rep) {
      const int i = base + rep * 1048576;  // 2*1048576 = 2097152 float4s total
      float4 v = reinterpret_cast<const float4*>(x)[i];
      ushort4 o;
      o.x = f2b(v.x); o.y = f2b(v.y); o.z = f2b(v.z); o.w = f2b(v.w);
      reinterpret_cast<ushort4*>(x_bf)[i] = o;
    }
    return;
  }
  __shared__ float tile[32][33];
  int bx = blockIdx.x;
  const float* in;
  u16* out;
  int Cc;
  if (z == 0)      { in = wq; out = wqkvt;              Cc = 2048; }
  else if (z == 1) { in = wo; out = wot;                Cc = 2048; }
  else {
    if (bx < 16)      { in = wk; out = wqkvt + 2048 * 2048; Cc = 512; }
    else if (bx < 32) { in = wv; out = wqkvt + 2560 * 2048; Cc = 512; bx -= 16; }
    else return;
  }
  const int R = 2048;
  const int c0 = bx * 32, r0 = blockIdx.y * 32;
  const int tx = threadIdx.x, ty = threadIdx.y;
  for (int i = ty; i < 32; i += 8) tile[i][tx] = in[(size_t)(r0 + i) * Cc + c0 + tx];
  __syncthreads();
  for (int i = ty; i < 32; i += 8) out[(size_t)(c0 + i) * R + r0 + tx] = f2b(tile[tx][i]);
}

// ---------------- bf16 GEMM: C[M][N] = A[M][K] * Bt[N][K]^T ----------------
// 128x128 tile, 4 waves (2x2), BK=64 (half the barrier drains of BK=32),
// XOR-swizzled LDS (T2; staging/read pattern identical to k_attn's verified
// V tile: [128 rows][8 x 16B units], unit ^= row&7, pre-swizzled global src +
// linear global_load_lds dest). kk-outer frag loop keeps live frags at 8.
// XCD-aware block swizzle (T1). 3 blocks/CU.
template <int OUT_BF16>
__global__ __launch_bounds__(256, 3) void k_gemm(const u16* __restrict__ A,
                                                 const u16* __restrict__ Bt,
                                                 void* __restrict__ Cp,
                                                 int M, int N, int Kd,
                                                 int lda, int ldb, int ldc) {
  __align__(16) __shared__ u16 As[128 * 64];  // 16 KB
  __align__(16) __shared__ u16 Bs[128 * 64];  // 16 KB
  const int tid = threadIdx.x;
  const int wid = tid >> 6, lane = tid & 63;
  const int lg = lane >> 4, lm = lane & 15;
  // XCD swizzle: consecutive swizzled ids within an XCD share the B panel.
  const int nwg = gridDim.x * gridDim.y;
  int f = blockIdx.y * gridDim.x + blockIdx.x;
  f = (f & 7) * (nwg >> 3) + (f >> 3);
  const int bm = f % gridDim.x, bn = f / gridDim.x;
  const int wr = wid >> 1, wc = wid & 1;

  // staging: 4 gload16/thread per matrix; g = tid + i*256, row = g>>3, u = g&7
  const u16* ap[4];
  const u16* bp[4];
#pragma unroll
  for (int i = 0; i < 4; ++i) {
    const int g = tid + i * 256;
    const int row = g >> 3, u = g & 7;
    ap[i] = A + (size_t)(bm * 128 + row) * lda + ((u ^ (row & 7)) * 8);
    bp[i] = Bt + (size_t)(bn * 128 + row) * ldb + ((u ^ (row & 7)) * 8);
  }

  // swizzled frag read offsets: row = (wr|wc)*64 + i*16 + lm -> row&7 = lm&7
  const int swzl = lm & 7;
  int aoff[4][2], boff[4][2];
#pragma unroll
  for (int i = 0; i < 4; ++i)
#pragma unroll
    for (int kk = 0; kk < 2; ++kk) {
      aoff[i][kk] = (wr * 64 + i * 16 + lm) * 64 + (((kk * 4 + lg) ^ swzl) * 8);
      boff[i][kk] = (wc * 64 + i * 16 + lm) * 64 + (((kk * 4 + lg) ^ swzl) * 8);
    }

  const f32x4 z4 = {0.f, 0.f, 0.f, 0.f};
  f32x4 acc[4][4];
#pragma unroll
  for (int i = 0; i < 4; ++i)
#pragma unroll
    for (int j = 0; j < 4; ++j) acc[i][j] = z4;

  const int nk = Kd >> 6;
  for (int kb = 0; kb < nk; ++kb) {
#pragma unroll
    for (int i = 0; i < 4; ++i) {
      const int g = tid + i * 256;
      gload16(ap[i], As + g * 8);
      gload16(bp[i], Bs + g * 8);
      ap[i] += 64;
      bp[i] += 64;
    }
    __syncthreads();
#pragma unroll
    for (int kk = 0; kk < 2; ++kk) {
      bf16x8 af[4], bfr[4];
#pragma unroll
      for (int i = 0; i < 4; ++i) {
        af[i] = *(const bf16x8*)(As + aoff[i][kk]);
        bfr[i] = *(const bf16x8*)(Bs + boff[i][kk]);
      }
#pragma unroll
      for (int i = 0; i < 4; ++i)
#pragma unroll
        for (int j = 0; j < 4; ++j)
          acc[i][j] = __builtin_amdgcn_mfma_f32_16x16x32_bf16(af[i], bfr[j], acc[i][j], 0, 0, 0);
    }
    __syncthreads();
  }

#pragma unroll
  for (int i = 0; i < 4; ++i) {
    const int row = bm * 128 + wr * 64 + i * 16 + lg * 4;
#pragma unroll
    for (int j = 0; j < 4; ++j) {
      const int col = bn * 128 + wc * 64 + j * 16 + lm;
#pragma unroll
      for (int r = 0; r < 4; ++r) {
        const float v = acc[i][j][r];
        if (OUT_BF16)
          ((u16*)Cp)[(size_t)(row + r) * ldc + col] = __builtin_bit_cast(u16, (__bf16)v);
        else
          ((float*)Cp)[(size_t)(row + r) * ldc + col] = v;
      }
    }
  }
}

// ---------------- fused: RoPE for K (bid<4096) + V transpose (bid>=4096) ----------------
__global__ void k_rope_v(const u16* __restrict__ qkv, u16* __restrict__ kbf,
                         u16* __restrict__ vt) {
  __shared__ u16 tile[32][33];
  const int bid = blockIdx.x;
  const int tid = threadIdx.x;
  if (bid < 4096) {
    const int idx = bid * 256 + tid;  // B*T*KVH*64 threads
    const int j = idx & 63;
    const int kh = (idx >> 6) & 3;
    const int m = idx >> 8;  // b*T + t
    const int t = m & (T_SEQ - 1);
    const int b = m >> 11;
    const float inv = __expf((float)j * -0.14391157f);
    const float ang = (float)t * inv;
    float s, c;
    __sincosf(ang, &s, &c);
    const u16* row = qkv + (size_t)m * 3072 + 2048 + kh * 128;
    const float x1 = b2f(row[j]), x2 = b2f(row[j + 64]);
    u16* orow = kbf + ((size_t)(b * KVH + kh) * T_SEQ + t) * 128;
    orow[j] = f2b(x1 * c - x2 * s);
    orow[j + 64] = f2b(x2 * c + x1 * s);
  } else {
    const int vb = bid - 4096;  // 2048 blocks
    const int t0 = (vb & 63) * 32, h0 = ((vb >> 6) & 3) * 32, bk = vb >> 8;
    const int b = bk >> 2, kh = bk & 3;
    const int tx = tid & 31, ty = tid >> 5;
    for (int i = ty; i < 32; i += 8)
      tile[i][tx] = qkv[(size_t)(b * T_SEQ + t0 + i) * 3072 + 2560 + kh * 128 + h0 + tx];
    __syncthreads();
    for (int i = ty; i < 32; i += 8)
      vt[(size_t)bk * (128 * T_SEQ) + (size_t)(h0 + i) * T_SEQ + t0 + tx] = tile[tx][i];
  }
}

// ---------------- Flash attention with tanh softcap + causal (R6/R8 verified) ----------------
// grid (16, N=16, B=2), 4 waves x 32 Q rows (two 16-row sub-tiles A,B).
// 2 blocks/CU. RoPE-Q fused into Q load. FIXED-MAX softmax. Pipelined P bounce.
__global__ __launch_bounds__(256, 2) void k_attn(const u16* __restrict__ qkv,
                                                 const u16* __restrict__ kbf,
                                                 const u16* __restrict__ vt,
                                                 u16* __restrict__ enc) {
  // LDS: Ks dbuf 2*16KB | Vs dbuf 2*16KB | Pl 4 waves * 2KB  = 73728 B
  __shared__ __align__(16) u16 smem[36864];
  u16* const Ks0 = smem;            // + buf*8192
  u16* const Vs0 = smem + 16384;    // + buf*8192

  const int n = blockIdx.y, b = blockIdx.z;
  const int qt = (b == 0) ? (15 - blockIdx.x) : blockIdx.x;  // balanced pairing
  const int kh = n >> 2;
  const int tid = threadIdx.x;
  const int wid = tid >> 6;
  const int lane = tid & 63;
  const int lg = lane >> 4;
  const int lm = lane & 15;
  const int q0w = qt * 128 + wid * 32;        // wave's first Q row
  u16* const Pl = smem + 32768 + wid * 1024;  // [16][64] bf16 swizzled, reused A->B

  // Q load from qkv + in-register RoPE + 1/sqrt(H) scale
  bf16x8 qfA[4], qfB[4];
  {
    const u16* qa = qkv + (size_t)(b * T_SEQ + q0w + lm) * 3072 + n * 128 + lg * 8;
    const u16* qb_ = qa + 16 * 3072;
    bf16x8 ra[4], rb[4];
#pragma unroll
    for (int c = 0; c < 4; ++c) {
      ra[c] = *(const bf16x8*)(qa + c * 32);
      rb[c] = *(const bf16x8*)(qb_ + c * 32);
    }
    const float scale = 0.08838834764831845f;  // 1/sqrt(128)
    const float tA = (float)(q0w + lm), tB = (float)(q0w + 16 + lm);
#pragma unroll
    for (int c = 0; c < 2; ++c) {
#pragma unroll
      for (int k = 0; k < 8; ++k) {
        const float inv = __expf((float)(c * 32 + lg * 8 + k) * -0.14391157f);
        float sA, cA, sB, cB;
        __sincosf(tA * inv, &sA, &cA);
        __sincosf(tB * inv, &sB, &cB);
        const float a1 = (float)ra[c][k], a2 = (float)ra[c + 2][k];
        const float b1 = (float)rb[c][k], b2 = (float)rb[c + 2][k];
        qfA[c][k]     = (__bf16)((a1 * cA - a2 * sA) * scale);
        qfA[c + 2][k] = (__bf16)((a2 * cA + a1 * sA) * scale);
        qfB[c][k]     = (__bf16)((b1 * cB - b2 * sB) * scale);
        qfB[c + 2][k] = (__bf16)((b2 * cB + b1 * sB) * scale);
      }
    }
  }
  const u16* const kg = kbf + (size_t)(b * KVH + kh) * T_SEQ * 128;
  const u16* const vg = vt + (size_t)(b * KVH + kh) * 128 * T_SEQ;

  // swizzled LDS read offsets (elements); 16B-unit ^= (row&7)
  const int swz = lm & 7;
  int koff[4], voff[2], poff[4];
#pragma unroll
  for (int c = 0; c < 4; ++c) koff[c] = lm * 128 + (((c * 4 + lg) ^ swz) * 8);
#pragma unroll
  for (int ks = 0; ks < 2; ++ks) voff[ks] = lm * 64 + (((ks * 4 + lg) ^ swz) * 8);
#pragma unroll
  for (int st = 0; st < 4; ++st)
    poff[st] = lm * 64 + (((st * 2 + (lg >> 1)) ^ swz) * 8) + (lg & 1) * 4;

  const f32x4 z4 = {0.f, 0.f, 0.f, 0.f};
  f32x4 accA[8], accB[8];
#pragma unroll
  for (int h = 0; h < 8; ++h) { accA[h] = z4; accB[h] = z4; }
  float lA = 0.f, lB = 0.f;  // per-lane partial row-sums

  const int ntiles = 2 * qt + 2;

  // stage tile kb2 into buffer buf (linear LDS dest, inverse-swizzled gsrc)
  auto STAGE = [&](int buf, int kb2) {
    const int kv2 = kb2 * 64;
    const u16* ksrc = kg + (size_t)kv2 * 128;
    u16* kdst = Ks0 + buf * 8192;
    u16* vdst = Vs0 + buf * 8192;
#pragma unroll
    for (int i = 0; i < 4; ++i) {
      const int g = tid + i * 256;
      const int row = g >> 4, u = g & 15;
      gload16(ksrc + row * 128 + ((u ^ (row & 7)) * 8), kdst + g * 8);
    }
#pragma unroll
    for (int i = 0; i < 4; ++i) {
      const int g = tid + i * 256;
      const int row = g >> 3, u = g & 7;
      gload16(vg + (size_t)row * T_SEQ + kv2 + ((u ^ (row & 7)) * 8), vdst + g * 8);
    }
  };

  // fixed-max softcap+softmax -> p[16]; no cross-lane ops.
  auto tile_pc = [&](f32x4* sa, float* p, float& lsum, int tg, bool needMask, int kv) {
#pragma unroll
    for (int st = 0; st < 4; ++st)
#pragma unroll
      for (int r = 0; r < 4; ++r) p[st * 4 + r] = sa[st][r];
    // p~ = exp(50*tanh(x/50) - 50) = exp2(-144.269504 / (exp2(x*0.05770780) + 1))
#pragma unroll
    for (int i = 0; i < 16; ++i) {
      const float e = __builtin_amdgcn_exp2f(p[i] * 0.05770780163555853f);
      p[i] = __builtin_amdgcn_exp2f(-144.269504088896f * __builtin_amdgcn_rcpf(e + 1.f));
    }
    if (needMask) {
#pragma unroll
      for (int i = 0; i < 16; ++i) {
        const int sg = kv + (i >> 2) * 16 + lg * 4 + (i & 3);
        if (sg > tg) p[i] = 0.f;
      }
    }
#pragma unroll
    for (int i = 0; i < 16; ++i) lsum += p[i];
  };
  // pack p[16] -> Pl via native bf16 casts (v_cvt_pk_bf16_f32)
  auto tile_pw = [&](const float* p) {
#pragma unroll
    for (int st = 0; st < 4; ++st) {
      bf16x4 w4;
#pragma unroll
      for (int r = 0; r < 4; ++r) w4[r] = (__bf16)p[st * 4 + r];
      *(bf16x4*)(Pl + poff[st]) = w4;
    }
  };

  STAGE(0, 0);
  asm volatile("s_waitcnt vmcnt(0)" ::: "memory");
  __syncthreads();

  for (int kb = 0; kb < ntiles; ++kb) {
    const int cur = kb & 1;
    if (kb + 1 < ntiles) STAGE(cur ^ 1, kb + 1);
    const int kv = kb * 64;
    if (kv <= q0w + 31) {  // wave has unmasked rows in this KV tile
      const u16* KsC = Ks0 + cur * 8192;
      const u16* VsC = Vs0 + cur * 8192;

      f32x4 saA[4] = {z4, z4, z4, z4};
      f32x4 saB[4] = {z4, z4, z4, z4};
      __builtin_amdgcn_s_setprio(1);
#pragma unroll
      for (int st = 0; st < 4; ++st) {
#pragma unroll
        for (int c = 0; c < 4; ++c) {
          const bf16x8 kf = *(const bf16x8*)(KsC + st * 2048 + koff[c]);
          saA[st] = __builtin_amdgcn_mfma_f32_16x16x32_bf16(kf, qfA[c], saA[st], 0, 0, 0);
          saB[st] = __builtin_amdgcn_mfma_f32_16x16x32_bf16(kf, qfB[c], saB[st], 0, 0, 0);
        }
      }
      __builtin_amdgcn_s_setprio(0);

      // pipelined P bounce: A's write latency hidden under B's softcap VALU
      float pA[16], pB[16];
      tile_pc(saA, pA, lA, q0w + lm, kv + 63 > q0w, kv);
      tile_pw(pA);
      tile_pc(saB, pB, lB, q0w + 16 + lm, kv + 63 > q0w + 16, kv);
      asm volatile("s_waitcnt lgkmcnt(0)" ::: "memory");
      bf16x8 pfA[2], pfB[2];
#pragma unroll
      for (int ks = 0; ks < 2; ++ks) pfA[ks] = *(const bf16x8*)(Pl + voff[ks]);
      tile_pw(pB);
      asm volatile("s_waitcnt lgkmcnt(0)" ::: "memory");
#pragma unroll
      for (int ks = 0; ks < 2; ++ks) pfB[ks] = *(const bf16x8*)(Pl + voff[ks]);

      __builtin_amdgcn_s_setprio(1);
#pragma unroll
      for (int h = 0; h < 8; ++h) {
#pragma unroll
        for (int ks = 0; ks < 2; ++ks) {
          const bf16x8 vf = *(const bf16x8*)(VsC + h * 1024 + voff[ks]);
          accA[h] = __builtin_amdgcn_mfma_f32_16x16x32_bf16(pfA[ks], vf, accA[h], 0, 0, 0);
          accB[h] = __builtin_amdgcn_mfma_f32_16x16x32_bf16(pfB[ks], vf, accB[h], 0, 0, 0);
        }
      }
      __builtin_amdgcn_s_setprio(0);
    }
    asm volatile("s_waitcnt vmcnt(0)" ::: "memory");  // next-tile staging landed
    __syncthreads();
  }

  // reduce row-sums across the 4 lg lanes sharing a row, then normalize.
  lA += __shfl_xor(lA, 16); lA += __shfl_xor(lA, 32);
  lB += __shfl_xor(lB, 16); lB += __shfl_xor(lB, 32);
  float liA[4], liB[4];
#pragma unroll
  for (int r = 0; r < 4; ++r) {
    liA[r] = 1.f / __shfl(lA, lg * 4 + r);
    liB[r] = 1.f / __shfl(lB, lg * 4 + r);
  }
#pragma unroll
  for (int h = 0; h < 8; ++h) {
#pragma unroll
    for (int r = 0; r < 4; ++r) {
      const size_t colo = n * 128 + h * 16 + lm;
      enc[(size_t)(b * T_SEQ + q0w + lg * 4 + r) * 2048 + colo] =
          __builtin_bit_cast(u16, (__bf16)(accA[h][r] * liA[r]));
      enc[(size_t)(b * T_SEQ + q0w + 16 + lg * 4 + r) * 2048 + colo] =
          __builtin_bit_cast(u16, (__bf16)(accB[h][r] * liB[r]));
    }
  }
}

extern "C" void kernel_launch(void* const* d_in, const int* in_sizes, int n_in,
                              void* d_out, int out_size, void* d_ws, size_t ws_size,
                              hipStream_t stream) {
  const float* x  = (const float*)d_in[0];
  const float* wq = (const float*)d_in[1];
  const float* wk = (const float*)d_in[2];
  const float* wv = (const float*)d_in[3];
  const float* wo = (const float*)d_in[4];

  char* ws = (char*)d_ws;
  u16* x_bf  = (u16*)(ws);                    // 16,777,216 B
  u16* wqkvt = (u16*)(ws + 16777216);         // 12,582,912 B  [3072][2048]
  u16* wot   = (u16*)(ws + 29360128);         //  8,388,608 B  [2048][2048]
  u16* qkv   = (u16*)(ws + 37748736);         // 25,165,824 B  [4096][3072] (live thru attn)
  u16* enc   = (u16*)(ws + 62914560);         // 16,777,216 B  [4096][2048]
  u16* k_bf  = (u16*)(ws + 79691776);         //  4,194,304 B  [b][kh][t][h]
  u16* vt    = (u16*)(ws + 83886080);         //  4,194,304 B  [b][kh][h][t]
  if (ws_size < 88080384) return;             // need 84 MiB scratch
  (void)in_sizes; (void)n_in; (void)out_size;

  // 1) prep: weight transposes + x -> bf16 (fused)
  k_prep<<<dim3(64, 64, 4), dim3(32, 8), 0, stream>>>(x, x_bf, wq, wk, wv, wo, wqkvt, wot);
  // 2) fused QKV projection: [4096][3072]
  k_gemm<1><<<dim3(32, 24), dim3(256), 0, stream>>>(x_bf, wqkvt, qkv,
                                                    4096, 3072, 2048, 2048, 2048, 3072);
  // 3) K RoPE + V transpose fused (Q RoPE fused into k_attn)
  k_rope_v<<<dim3(6144), dim3(256), 0, stream>>>(qkv, k_bf, vt);
  // 4) flash attention -> enc [4096][2048] bf16
  k_attn<<<dim3(16, 16, 2), dim3(256), 0, stream>>>(qkv, k_bf, vt, enc);
  // 5) output projection -> d_out fp32
  k_gemm<0><<<dim3(32, 16), dim3(256), 0, stream>>>(enc, wot, d_out,
                                                    4096, 2048, 2048, 2048, 2048, 2048);
}